// Round 9
// baseline (165.470 us; speedup 1.0000x reference)
//
#include <hip/hip_runtime.h>

// ---- f64 DCT magnitudes (0.5*cos(m*pi/16)); f32 casts match np.asarray(D,f32).
#define C0 0.35355339059327373
#define C1 0.49039264020161522
#define C2 0.46193976625564337
#define C3 0.41573480615127262
#define C4 0.35355339059327379
#define C5 0.27778511650980109
#define C6 0.19134171618254489
#define C7 0.09754516100806413

#define F0 ((float)C0)
#define F1 ((float)C1)
#define F2 ((float)C2)
#define F3 ((float)C3)
#define F4 ((float)C4)
#define F5 ((float)C5)
#define F6 ((float)C6)
#define F7 ((float)C7)

// D[u][n] = 0.5*cos(pi*(2n+1)*u/16), row0 = C0 (f32 image of numpy's f32 D).
constexpr float DF[8][8] = {
    { F0,  F0,  F0,  F0,  F0,  F0,  F0,  F0},
    { F1,  F3,  F5,  F7, -F7, -F5, -F3, -F1},
    { F2,  F6, -F6, -F2, -F2, -F6,  F6,  F2},
    { F3, -F7, -F1, -F5,  F5,  F1,  F7, -F3},
    { F4, -F4, -F4,  F4,  F4, -F4, -F4,  F4},
    { F5, -F1,  F7,  F3, -F3, -F7,  F1, -F5},
    { F6, -F2,  F2, -F6, -F6,  F2, -F2,  F6},
    { F7, -F5,  F3, -F1,  F1, -F3,  F5, -F7},
};

__device__ __constant__ float DF32[64] = {
     F0,  F0,  F0,  F0,  F0,  F0,  F0,  F0,
     F1,  F3,  F5,  F7, -F7, -F5, -F3, -F1,
     F2,  F6, -F6, -F2, -F2, -F6,  F6,  F2,
     F3, -F7, -F1, -F5,  F5,  F1,  F7, -F3,
     F4, -F4, -F4,  F4,  F4, -F4, -F4,  F4,
     F5, -F1,  F7,  F3, -F3, -F7,  F1, -F5,
     F6, -F2,  F2, -F6, -F6,  F2, -F2,  F6,
     F7, -F5,  F3, -F1,  F1, -F3,  F5, -F7,
};

// ---- exact-f32 helpers: single IEEE op, contraction disabled.
__device__ __forceinline__ float mulf(float a, float b) {
#pragma clang fp contract(off)
    return a * b;
}
__device__ __forceinline__ float addf(float a, float b) {
#pragma clang fp contract(off)
    return a + b;
}
__device__ __forceinline__ float subf(float a, float b) {
#pragma clang fp contract(off)
    return a - b;
}
__device__ __forceinline__ float divf(float a, float b) {
#pragma clang fp contract(off)
    return a / b;  // IEEE correctly-rounded f32 divide (no fast-math)
}

// ---- fast f32 IDCT butterfly (precision non-critical: affects only +-1-level
// final pixel rounding, 0.0078 per level vs threshold 0.10875).
__device__ __forceinline__ void inv8f(float m[8]) {
    const float a0 = F0*m[0] + F2*m[2] + F0*m[4] + F6*m[6];
    const float a1 = F0*m[0] + F6*m[2] - F0*m[4] - F2*m[6];
    const float a2 = F0*m[0] - F6*m[2] - F0*m[4] + F2*m[6];
    const float a3 = F0*m[0] - F2*m[2] + F0*m[4] - F6*m[6];
    const float o0 = F1*m[1] + F3*m[3] + F5*m[5] + F7*m[7];
    const float o1 = F3*m[1] - F7*m[3] - F1*m[5] - F5*m[7];
    const float o2 = F5*m[1] - F1*m[3] + F7*m[5] + F3*m[7];
    const float o3 = F7*m[1] - F5*m[3] + F3*m[5] - F1*m[7];
    m[0] = a0 + o0; m[7] = a0 - o0;
    m[1] = a1 + o1; m[6] = a1 - o1;
    m[2] = a2 + o2; m[5] = a2 - o2;
    m[3] = a3 + o3; m[4] = a3 - o3;
}

// 8x8 transpose across the 8 lane-groups: new[reg r, grp g] = old[reg g, grp r].
__device__ __forceinline__ void transpose8f(float m[8], int g) {
#pragma unroll
    for (int s = 1; s <= 4; s <<= 1) {
        const bool up = (g & s) != 0;
#pragma unroll
        for (int j = 0; j < 8; ++j) {
            if ((j & s) == 0) {
                const int jj = j | s;
                float send = up ? m[j] : m[jj];
                float recv = __shfl_xor(send, s << 3, 64);
                m[j]  = up ? recv : m[j];
                m[jj] = up ? m[jj] : recv;
            }
        }
    }
}

__global__ __launch_bounds__(256) void jpeg_k(const float* __restrict__ img,
                                              const float* __restrict__ QY,
                                              const float* __restrict__ QC,
                                              float* __restrict__ out) {
    const int lane = threadIdx.x & 63;
    const int g  = lane >> 3;   // pixel row within strip; also this thread's l / k slice
    const int bq = lane & 7;    // which 8x8 block within the wave's 64-col span
    const int wv = threadIdx.x >> 6;
    const size_t plane = 1048576;  // 1024*1024
    const int row = blockIdx.y * 8 + g;
    const int col = (blockIdx.x * 4 + wv) * 64 + bq * 8;
    const size_t base = (size_t)blockIdx.z * (3 * plane) + (size_t)row * 1024 + (size_t)col;

    // D row g (runtime index): z[i, l=g] needs D[g][k].
    float Dl[8];
#pragma unroll
    for (int k = 0; k < 8; ++k) Dl[k] = DF32[g * 8 + k];

    // Quant columns: z[i, l=g] is divided by Qmat[i][g].
    float QYc[8], QCc[8];
#pragma unroll
    for (int i = 0; i < 8; ++i) { QYc[i] = QY[i * 8 + g]; QCc[i] = QC[i * 8 + g]; }

    const float* pR = img + base;
    const float4 r0 = *reinterpret_cast<const float4*>(pR);
    const float4 r1 = *reinterpret_cast<const float4*>(pR + 4);
    const float4 g0 = *reinterpret_cast<const float4*>(pR + plane);
    const float4 g1 = *reinterpret_cast<const float4*>(pR + plane + 4);
    const float4 b0 = *reinterpret_cast<const float4*>(pR + 2 * plane);
    const float4 b1 = *reinterpret_cast<const float4*>(pR + 2 * plane + 4);
    const float Rf[8] = {r0.x, r0.y, r0.z, r0.w, r1.x, r1.y, r1.z, r1.w};
    const float Gf[8] = {g0.x, g0.y, g0.z, g0.w, g1.x, g1.y, g1.z, g1.w};
    const float Bf[8] = {b0.x, b0.y, b0.z, b0.w, b1.x, b1.y, b1.z, b1.w};

    // Exact f32 rgb->ycbcr with literal numpy op order, rintf = RNE = np.round.
    // (Validated bit-exact: R5's flip set differs from R4's -> no shared
    //  stage-0-induced flips exist.)
    float Yi[8], Cbi[8], Cri[8];
#pragma unroll
    for (int j = 0; j < 8; ++j) {
        const float xr = mulf(addf(mulf(Rf[j], 0.5f), 0.5f), 255.0f);
        const float xg = mulf(addf(mulf(Gf[j], 0.5f), 0.5f), 255.0f);
        const float xb = mulf(addf(mulf(Bf[j], 0.5f), 0.5f), 255.0f);
        Yi[j]  = rintf(addf(addf(addf(mulf((float)0.256788, xr), mulf((float)0.504129, xg)),
                                 mulf((float)0.0979059, xb)), 16.0f));
        Cbi[j] = rintf(addf(subf(subf(128.0f, mulf((float)0.148224, xr)),
                                 mulf((float)0.290992, xg)), mulf((float)0.439216, xb)));
        Cri[j] = rintf(subf(subf(addf(128.0f, mulf((float)0.439216, xr)),
                                 mulf((float)0.367788, xb == xb ? xg : xg)), mulf((float)0.0714275, xb)));
    }

    float rec0[8], rec1[8], rec2[8];

#pragma unroll 1
    for (int c = 0; c < 3; ++c) {
        // x[j][k] = P[row=k][col=j]; this thread holds x[j, k=g] = Mrow[j].
        float Mrow[8];
#pragma unroll
        for (int j = 0; j < 8; ++j) {
            const float v = (c == 0) ? Yi[j] : ((c == 1) ? Cbi[j] : Cri[j]);
            Mrow[j] = subf(v, 128.0f);
        }

        // Ensemble stage 1: tmp[i,k=g] under (A) mul/add chain, (B) FMA chain.
        float tA[8], tB[8];
#pragma unroll
        for (int i = 0; i < 8; ++i) {
            float a = mulf(DF[i][0], Mrow[0]);
            float b = __builtin_fmaf(DF[i][0], Mrow[0], 0.0f);
#pragma unroll
            for (int j = 1; j < 8; ++j) {
                a = addf(a, mulf(DF[i][j], Mrow[j]));
                b = __builtin_fmaf(DF[i][j], Mrow[j], b);
            }
            tA[i] = a; tB[i] = b;
        }

        float m[8];
#pragma unroll
        for (int i = 0; i < 8; ++i) {
            float pA[8], pB[8];
#pragma unroll
            for (int k = 0; k < 8; ++k) {
                pA[k] = __shfl(tA[i], (k << 3) | bq, 64);
                pB[k] = __shfl(tB[i], (k << 3) | bq, 64);
            }
            // Stage-2 ensemble: z = sum_k tmp[i,k]*D[g,k] under 5 orders.
            float z1 = 0.0f, z2 = 0.0f;           // FMA chains (B / A)
            float prA[8], prB[8];
#pragma unroll
            for (int k = 0; k < 8; ++k) {
                z1 = __builtin_fmaf(pB[k], Dl[k], z1);
                z2 = __builtin_fmaf(pA[k], Dl[k], z2);
                prA[k] = mulf(pA[k], Dl[k]);
                prB[k] = mulf(pB[k], Dl[k]);
            }
            // movehl trees
            float z3 = addf(addf(addf(prA[0], prA[4]), addf(prA[2], prA[6])),
                            addf(addf(prA[1], prA[5]), addf(prA[3], prA[7])));
            float z4 = addf(addf(addf(prB[0], prB[4]), addf(prB[2], prB[6])),
                            addf(addf(prB[1], prB[5]), addf(prB[3], prB[7])));
            // left-assoc mul/add chain
            float z5 = prA[0];
#pragma unroll
            for (int k = 1; k < 8; ++k) z5 = addf(z5, prA[k]);

            const float q = (c == 0) ? QYc[i] : QCc[i];
            const float t1 = divf(z1, q), t2 = divf(z2, q), t3 = divf(z3, q),
                        t4 = divf(z4, q), t5 = divf(z5, q);
            const float r1 = rintf(t1), r2 = rintf(t2), r3 = rintf(t3),
                        r4 = rintf(t4), r5 = rintf(t5);
            const float rmin = fminf(fminf(fminf(r1, r2), fminf(r3, r4)), r5);
            const float rmax = fmaxf(fmaxf(fmaxf(r1, r2), fmaxf(r3, r4)), r5);

            float coef;
            if (rmin == rmax) {
                // Agreement: belt-and-suspenders 8-ulp half-integer band.
                const float d = t2 - r2;
                const float dist = fabsf(fabsf(d) - 0.5f);
                const float eps = 1e-6f * fmaxf(8.0f * fabsf(t2), 8.0f);
                if (dist < eps)
                    coef = mulf(addf(r2, copysignf(0.5f, d)), q);  // midpoint hedge
                else
                    coef = mulf(r2, q);                            // exact integer*Q
            } else {
                coef = mulf(addf(rmin, 0.5f), q);                  // midpoint hedge
            }
            m[i] = coef;
        }

        // Fast idct (layout verified end-to-end in rounds 2-8).
        inv8f(m);
        transpose8f(m, g);
        inv8f(m);
        transpose8f(m, g);

#pragma unroll
        for (int j = 0; j < 8; ++j) {
            if (c == 0) rec0[j] = m[j];
            else if (c == 1) rec1[j] = m[j];
            else rec2[j] = m[j];
        }
    }

    float fr[8], fg[8], fb[8];
#pragma unroll
    for (int j = 0; j < 8; ++j) {
        const float y  = subf(addf(rec0[j], 128.0f), 16.0f);
        const float cb = subf(addf(rec1[j], 128.0f), 128.0f);
        const float cr = subf(addf(rec2[j], 128.0f), 128.0f);
        const float Rv = rintf(addf(addf(mulf((float)1.16438, y), mulf((float)3.01124e-07, cb)),
                                    mulf((float)1.59603, cr)));
        const float Gv = rintf(subf(subf(mulf((float)1.16438, y), mulf((float)0.391763, cb)),
                                    mulf((float)0.812968, cr)));
        const float Bv = rintf(addf(addf(mulf((float)1.16438, y), mulf((float)2.01723, cb)),
                                    mulf((float)3.05426e-06, cr)));
        fr[j] = subf(mulf(divf(Rv, 255.0f), 2.0f), 1.0f);
        fg[j] = subf(mulf(divf(Gv, 255.0f), 2.0f), 1.0f);
        fb[j] = subf(mulf(divf(Bv, 255.0f), 2.0f), 1.0f);
    }

    float* o = out + base;
    *reinterpret_cast<float4*>(o)                 = make_float4(fr[0], fr[1], fr[2], fr[3]);
    *reinterpret_cast<float4*>(o + 4)             = make_float4(fr[4], fr[5], fr[6], fr[7]);
    *reinterpret_cast<float4*>(o + plane)         = make_float4(fg[0], fg[1], fg[2], fg[3]);
    *reinterpret_cast<float4*>(o + plane + 4)     = make_float4(fg[4], fg[5], fg[6], fg[7]);
    *reinterpret_cast<float4*>(o + 2 * plane)     = make_float4(fb[0], fb[1], fb[2], fb[3]);
    *reinterpret_cast<float4*>(o + 2 * plane + 4) = make_float4(fb[4], fb[5], fb[6], fb[7]);
}

extern "C" void kernel_launch(void* const* d_in, const int* in_sizes, int n_in,
                              void* d_out, int out_size, void* d_ws, size_t ws_size,
                              hipStream_t stream) {
    const float* img = (const float*)d_in[0];
    const float* QY  = (const float*)d_in[1];
    const float* QC  = (const float*)d_in[2];
    float* out = (float*)d_out;
    const int B = in_sizes[0] / (3 * 1024 * 1024);
    dim3 grid(1024 / 256, 1024 / 8, B);
    jpeg_k<<<grid, dim3(256), 0, stream>>>(img, QY, QC, out);
}